// Round 1
// baseline (1233.869 us; speedup 1.0000x reference)
//
#include <hip/hip_runtime.h>

// Problem constants
#define DIM   180
#define HEADS 6
#define HD    30
#define NKEY  144
#define NGS   2304
#define BATCH 64
#define TQ    32
#define QTILES (NGS / TQ)     // 72
#define KC4   (DIM / 4)       // 45 float4 per row
#define SL_STRIDE 148         // bf16 elements per logit row (padded: 148 -> bank stride 74 mod 32 = 10)
#define KV_STRIDE 145         // float4 per d-chunk row (padded: 145*4 mod 32 = 4 -> conflict-free)

// bf16 <-> f32 helpers (RNE on pack)
__device__ __forceinline__ float bf2f(unsigned short u) {
    union { unsigned int i; float f; } w;
    w.i = ((unsigned int)u) << 16;
    return w.f;
}
__device__ __forceinline__ unsigned short f2bf(float f) {
    union { float f; unsigned int i; } w;
    w.f = f;
    unsigned int r = w.i + 0x7fffu + ((w.i >> 16) & 1u);
    return (unsigned short)(r >> 16);
}
__device__ __forceinline__ void fma4(float4& a, float p, const float4& v) {
    a.x = fmaf(p, v.x, a.x);
    a.y = fmaf(p, v.y, a.y);
    a.z = fmaf(p, v.z, a.z);
    a.w = fmaf(p, v.w, a.w);
}

// ---------------------------------------------------------------------------
// Kernel 1: pre-gather relative-position bias: biasg[h][q][n] = table[rpi[q,n]][h]
// grid = NGS*NKEY/256 = 1296 exactly, block = 256
__global__ __launch_bounds__(256) void gather_bias_kernel(
    const float* __restrict__ table, const int* __restrict__ rpi,
    float* __restrict__ biasg) {
    int idx = blockIdx.x * 256 + threadIdx.x;   // < NGS*NKEY exactly
    int r = rpi[idx];
    int q = idx / NKEY, n = idx % NKEY;
#pragma unroll
    for (int h = 0; h < HEADS; ++h)
        biasg[(h * NGS + q) * NKEY + n] = table[r * HEADS + h];
}

// ---------------------------------------------------------------------------
// Kernel 2: K = feat@Wk + bk, V = feat@Wv + bv   (natural [b][n][DIM] layout)
// grid = 64*9 = 576, block = 256; 16 feat rows per block
__global__ __launch_bounds__(256) void kv_proj_kernel(
    const float* __restrict__ feat,
    const float* __restrict__ Wk, const float* __restrict__ bk,
    const float* __restrict__ Wv, const float* __restrict__ bv,
    float* __restrict__ Kout, float* __restrict__ Vout) {
    __shared__ float sF[16 * DIM];
    int b  = blockIdx.x / 9;
    int n0 = (blockIdx.x % 9) * 16;
    int tid = threadIdx.x;

    {
        const float4* src = (const float4*)(feat + (b * NKEY + n0) * DIM);
        float4* dst = (float4*)sF;
        for (int i = tid; i < 16 * KC4; i += 256) dst[i] = src[i];
    }
    __syncthreads();

    int j = tid;
    if (j < DIM) {
        float ak[16], av[16];
#pragma unroll
        for (int r = 0; r < 16; ++r) { ak[r] = 0.f; av[r] = 0.f; }
        const float4* sF4 = (const float4*)sF;
        for (int kc = 0; kc < KC4; ++kc) {
            int kk = kc * 4;
            float wk0 = Wk[(kk + 0) * DIM + j];
            float wk1 = Wk[(kk + 1) * DIM + j];
            float wk2 = Wk[(kk + 2) * DIM + j];
            float wk3 = Wk[(kk + 3) * DIM + j];
            float wv0 = Wv[(kk + 0) * DIM + j];
            float wv1 = Wv[(kk + 1) * DIM + j];
            float wv2 = Wv[(kk + 2) * DIM + j];
            float wv3 = Wv[(kk + 3) * DIM + j];
#pragma unroll
            for (int r = 0; r < 16; ++r) {
                float4 g = sF4[r * KC4 + kc];
                ak[r] = fmaf(g.x, wk0, ak[r]);
                ak[r] = fmaf(g.y, wk1, ak[r]);
                ak[r] = fmaf(g.z, wk2, ak[r]);
                ak[r] = fmaf(g.w, wk3, ak[r]);
                av[r] = fmaf(g.x, wv0, av[r]);
                av[r] = fmaf(g.y, wv1, av[r]);
                av[r] = fmaf(g.z, wv2, av[r]);
                av[r] = fmaf(g.w, wv3, av[r]);
            }
        }
        float bkj = bk[j], bvj = bv[j];
#pragma unroll
        for (int r = 0; r < 16; ++r) {
            Kout[(b * NKEY + n0 + r) * DIM + j] = ak[r] + bkj;
            Vout[(b * NKEY + n0 + r) * DIM + j] = av[r] + bvj;
        }
    }
}

// ---------------------------------------------------------------------------
// Kernel 3: fused Q-proj -> per-head (QK^T + bias -> softmax -> PV) -> out-proj
// grid = 64*72 = 4608, block = 256. One block = one (batch, 32-query tile).
// Static LDS = 23040 + 12288 + 18560 + 9472 = 63360 B (<64 KB -> 2 blocks/CU)
__global__ __launch_bounds__(256, 2) void attn_kernel(
    const float* __restrict__ gs,
    const float* __restrict__ Wq, const float* __restrict__ bq,
    const float* __restrict__ Wp, const float* __restrict__ bp,
    const float* __restrict__ K, const float* __restrict__ V,
    const float* __restrict__ biasg, float* __restrict__ out) {

    __shared__ float          sX[TQ * DIM];            // gs tile, later x tile
    __shared__ unsigned short sQ[HEADS * TQ * 32];     // bf16 Q, per-head slabs [h][q][32]
    __shared__ float4         sKV4[8 * KV_STRIDE];     // K_h / V_h, chunked: [u=d/4][n] float4
    __shared__ unsigned short sL[TQ * SL_STRIDE];      // bf16 logits / probs

    int tid = threadIdx.x;
    int b   = blockIdx.x / QTILES;
    int q0  = (blockIdx.x % QTILES) * TQ;
    float* sKVf = (float*)sKV4;

    // ---- load gs tile (contiguous 32*180 floats) ----
    {
        const float4* src = (const float4*)(gs + (b * NGS + q0) * DIM);
        float4* dst = (float4*)sX;
        for (int i = tid; i < TQ * KC4; i += 256) dst[i] = src[i];
    }
    __syncthreads();

    // ---- phase 1: Q = (gs @ Wq + bq) * scale -> sQ (bf16) ----
    const float SCALE = 0.18257418583505536f;   // 1/sqrt(30)
    if (tid < DIM) {
        int j = tid;
        float acc[TQ];
#pragma unroll
        for (int r = 0; r < TQ; ++r) acc[r] = 0.f;
        const float4* sX4 = (const float4*)sX;
        for (int kc = 0; kc < KC4; ++kc) {
            float w0 = Wq[(4 * kc + 0) * DIM + j];
            float w1 = Wq[(4 * kc + 1) * DIM + j];
            float w2 = Wq[(4 * kc + 2) * DIM + j];
            float w3 = Wq[(4 * kc + 3) * DIM + j];
#pragma unroll
            for (int r = 0; r < TQ; ++r) {
                float4 g = sX4[r * KC4 + kc];
                acc[r] = fmaf(g.x, w0, acc[r]);
                acc[r] = fmaf(g.y, w1, acc[r]);
                acc[r] = fmaf(g.z, w2, acc[r]);
                acc[r] = fmaf(g.w, w3, acc[r]);
            }
        }
        float bj = bq[j];
        int h = j / HD, dl = j % HD;
#pragma unroll
        for (int r = 0; r < TQ; ++r)
            sQ[(h * TQ + r) * 32 + dl] = f2bf((acc[r] + bj) * SCALE);
    }
    // zero-pad Q columns d=30,31 of each head slab (K pad is also zeroed; keeps FMAs clean)
    for (int i = tid; i < HEADS * TQ * 2; i += 256) {
        int hq = i >> 1;
        sQ[hq * 32 + 30 + (i & 1)] = 0;
    }
    __syncthreads();

    // ---- per-head attention ----
    for (int h = 0; h < HEADS; ++h) {
        // (a) stage K_h into chunked LDS layout, zero-pad d=30,31
        {
            const float* src = K + (b * NKEY) * DIM + h * HD;
            for (int idx = tid; idx < NKEY * HD; idx += 256) {
                int n = idx / HD, dl = idx % HD;
                sKVf[((dl >> 2) * KV_STRIDE + n) * 4 + (dl & 3)] = src[n * DIM + dl];
            }
            for (int idx = tid; idx < NKEY * 2; idx += 256) {
                int n = idx >> 1;
                sKVf[(7 * KV_STRIDE + n) * 4 + 2 + (idx & 1)] = 0.f;
            }
        }
        __syncthreads();

        // (b) logits = Q_h K_h^T + bias -> sL (bf16)
        {
            int tx = tid & 15, ty = tid >> 4;
            float acc[2][9];
#pragma unroll
            for (int qq = 0; qq < 2; ++qq)
#pragma unroll
                for (int k = 0; k < 9; ++k) acc[qq][k] = 0.f;
#pragma unroll
            for (int u = 0; u < 8; ++u) {
                float qa[2][4];
#pragma unroll
                for (int qq = 0; qq < 2; ++qq) {
                    int q = ty + 16 * qq;
                    ushort4 qv = *(const ushort4*)&sQ[(h * TQ + q) * 32 + 4 * u];
                    qa[qq][0] = bf2f(qv.x); qa[qq][1] = bf2f(qv.y);
                    qa[qq][2] = bf2f(qv.z); qa[qq][3] = bf2f(qv.w);
                }
#pragma unroll
                for (int k = 0; k < 9; ++k) {
                    int n = tx + 16 * k;
                    float4 kv = sKV4[u * KV_STRIDE + n];
#pragma unroll
                    for (int qq = 0; qq < 2; ++qq) {
                        acc[qq][k] = fmaf(qa[qq][0], kv.x, acc[qq][k]);
                        acc[qq][k] = fmaf(qa[qq][1], kv.y, acc[qq][k]);
                        acc[qq][k] = fmaf(qa[qq][2], kv.z, acc[qq][k]);
                        acc[qq][k] = fmaf(qa[qq][3], kv.w, acc[qq][k]);
                    }
                }
            }
            const float* bg = biasg + (h * NGS + q0) * NKEY;
#pragma unroll
            for (int qq = 0; qq < 2; ++qq) {
                int q = ty + 16 * qq;
#pragma unroll
                for (int k = 0; k < 9; ++k) {
                    int n = tx + 16 * k;
                    sL[q * SL_STRIDE + n] = f2bf(acc[qq][k] + bg[q * NKEY + n]);
                }
            }
        }
        __syncthreads();

        // (c) softmax over 144 keys (8 lanes per query) + (d) stage V_h
        {
            int q = tid >> 3, l8 = tid & 7;
            float lv[18];
            float m = -1e30f;
#pragma unroll
            for (int u = 0; u < 18; ++u) {
                lv[u] = bf2f(sL[q * SL_STRIDE + l8 + 8 * u]);
                m = fmaxf(m, lv[u]);
            }
            m = fmaxf(m, __shfl_xor(m, 1, 8));
            m = fmaxf(m, __shfl_xor(m, 2, 8));
            m = fmaxf(m, __shfl_xor(m, 4, 8));
            float s = 0.f;
#pragma unroll
            for (int u = 0; u < 18; ++u) { lv[u] = __expf(lv[u] - m); s += lv[u]; }
            s += __shfl_xor(s, 1, 8);
            s += __shfl_xor(s, 2, 8);
            s += __shfl_xor(s, 4, 8);
            float inv = 1.f / s;
#pragma unroll
            for (int u = 0; u < 18; ++u)
                sL[q * SL_STRIDE + l8 + 8 * u] = f2bf(lv[u] * inv);

            // (d) V_h -> same chunked buffer (K reads all completed before prior barrier)
            const float* src = V + (b * NKEY) * DIM + h * HD;
            for (int idx = tid; idx < NKEY * HD; idx += 256) {
                int n = idx / HD, dl = idx % HD;
                sKVf[((dl >> 2) * KV_STRIDE + n) * 4 + (dl & 3)] = src[n * DIM + dl];
            }
            for (int idx = tid; idx < NKEY * 2; idx += 256) {
                int n = idx >> 1;
                sKVf[(7 * KV_STRIDE + n) * 4 + 2 + (idx & 1)] = 0.f;
            }
        }
        __syncthreads();

        // (e) x_h = P @ V_h : thread = (q-pair, n-quarter, u-pair), xor-reduce over n-quarters
        {
            int ty = tid >> 4;                 // q-pair index 0..15
            int tx = tid & 15;
            int nq = tx >> 2, c4 = tx & 3;     // n-quarter, u in {c4, c4+4}
            float4 xa[2][2];
#pragma unroll
            for (int qq = 0; qq < 2; ++qq)
#pragma unroll
                for (int uu = 0; uu < 2; ++uu) xa[qq][uu] = make_float4(0.f, 0.f, 0.f, 0.f);
            int nbase = nq * 36;
            for (int nn = 0; nn < 36; nn += 2) {
                int n = nbase + nn;
                ushort2 pA = *(const ushort2*)&sL[(2 * ty) * SL_STRIDE + n];
                ushort2 pB = *(const ushort2*)&sL[(2 * ty + 1) * SL_STRIDE + n];
                float p00 = bf2f(pA.x), p01 = bf2f(pA.y);
                float p10 = bf2f(pB.x), p11 = bf2f(pB.y);
#pragma unroll
                for (int uu = 0; uu < 2; ++uu) {
                    int u = c4 + 4 * uu;
                    float4 v0 = sKV4[u * KV_STRIDE + n];
                    float4 v1 = sKV4[u * KV_STRIDE + n + 1];
                    fma4(xa[0][uu], p00, v0);
                    fma4(xa[0][uu], p01, v1);
                    fma4(xa[1][uu], p10, v0);
                    fma4(xa[1][uu], p11, v1);
                }
            }
#pragma unroll
            for (int qq = 0; qq < 2; ++qq)
#pragma unroll
                for (int uu = 0; uu < 2; ++uu) {
                    xa[qq][uu].x += __shfl_xor(xa[qq][uu].x, 4);
                    xa[qq][uu].y += __shfl_xor(xa[qq][uu].y, 4);
                    xa[qq][uu].z += __shfl_xor(xa[qq][uu].z, 4);
                    xa[qq][uu].w += __shfl_xor(xa[qq][uu].w, 4);
                    xa[qq][uu].x += __shfl_xor(xa[qq][uu].x, 8);
                    xa[qq][uu].y += __shfl_xor(xa[qq][uu].y, 8);
                    xa[qq][uu].z += __shfl_xor(xa[qq][uu].z, 8);
                    xa[qq][uu].w += __shfl_xor(xa[qq][uu].w, 8);
                }
            if (nq == 0) {
#pragma unroll
                for (int qq = 0; qq < 2; ++qq) {
                    int q = 2 * ty + qq;
                    float* xrow = sX + q * DIM + h * HD;
#pragma unroll
                    for (int uu = 0; uu < 2; ++uu) {
                        int u = c4 + 4 * uu;
                        int dbase = 4 * u;
                        xrow[dbase + 0] = xa[qq][uu].x;
                        xrow[dbase + 1] = xa[qq][uu].y;
                        if (dbase + 2 < HD) {
                            xrow[dbase + 2] = xa[qq][uu].z;
                            xrow[dbase + 3] = xa[qq][uu].w;
                        }
                    }
                }
            }
        }
        __syncthreads();
    }

    // ---- phase 3: out = x @ Wp + bp ----
    if (tid < DIM) {
        int j = tid;
        float acc[TQ];
#pragma unroll
        for (int r = 0; r < TQ; ++r) acc[r] = 0.f;
        const float4* sX4 = (const float4*)sX;
        for (int kc = 0; kc < KC4; ++kc) {
            float w0 = Wp[(4 * kc + 0) * DIM + j];
            float w1 = Wp[(4 * kc + 1) * DIM + j];
            float w2 = Wp[(4 * kc + 2) * DIM + j];
            float w3 = Wp[(4 * kc + 3) * DIM + j];
#pragma unroll
            for (int r = 0; r < TQ; ++r) {
                float4 g = sX4[r * KC4 + kc];
                acc[r] = fmaf(g.x, w0, acc[r]);
                acc[r] = fmaf(g.y, w1, acc[r]);
                acc[r] = fmaf(g.z, w2, acc[r]);
                acc[r] = fmaf(g.w, w3, acc[r]);
            }
        }
        float bj = bp[j];
        float* dst = out + (b * NGS + q0) * DIM;
#pragma unroll
        for (int r = 0; r < TQ; ++r) dst[r * DIM + j] = acc[r] + bj;
    }
}

// ---------------------------------------------------------------------------
extern "C" void kernel_launch(void* const* d_in, const int* in_sizes, int n_in,
                              void* d_out, int out_size, void* d_ws, size_t ws_size,
                              hipStream_t stream) {
    const float* gs    = (const float*)d_in[0];
    const float* feat  = (const float*)d_in[1];
    const float* Wq    = (const float*)d_in[2];
    const float* bq    = (const float*)d_in[3];
    const float* Wk    = (const float*)d_in[4];
    const float* bk    = (const float*)d_in[5];
    const float* Wv    = (const float*)d_in[6];
    const float* bv    = (const float*)d_in[7];
    const float* Wp    = (const float*)d_in[8];
    const float* bp    = (const float*)d_in[9];
    const float* table = (const float*)d_in[10];
    const int*   rpi   = (const int*)d_in[11];
    float* out = (float*)d_out;

    // workspace: K [64][144][180] f32 | V [64][144][180] f32 | biasg [6][2304][144] f32
    // = 6,635,520 + 6,635,520 + 7,962,624 = 21,233,664 bytes
    float* Kw    = (float*)d_ws;
    float* Vw    = Kw + BATCH * NKEY * DIM;
    float* biasg = Vw + BATCH * NKEY * DIM;

    gather_bias_kernel<<<dim3(NGS * NKEY / 256), dim3(256), 0, stream>>>(table, rpi, biasg);
    kv_proj_kernel<<<dim3(BATCH * 9), dim3(256), 0, stream>>>(feat, Wk, bk, Wv, bv, Kw, Vw);
    attn_kernel<<<dim3(BATCH * QTILES), dim3(256), 0, stream>>>(
        gs, Wq, bq, Wp, bp, Kw, Vw, biasg, out);
}

// Round 3
// 447.072 us; speedup vs baseline: 2.7599x; 2.7599x over previous
//
#include <hip/hip_runtime.h>

// Problem constants
#define DIM   180
#define HEADS 6
#define HD    30
#define NKEY  144
#define NGS   2304
#define BATCH 64
#define TQ    64
#define QT    (NGS / TQ)        // 36 q-tiles
#define WPAD  192               // padded model dim (6 k-tiles of 32)
// LDS strides (elements). Chosen so ds_read_b128 fragment patterns are <=2-way
// bank aliased: stride(dwords) mod 32 = {4, 4, 12, 12, 20} -> period-8 lane cycle.
#define SXS   200               // x / gs tile rows
#define SQS   200               // Q rows
#define SPS   152               // P rows (144 keys + 8 pad, pad never read)
#define SVS   152               // V^T rows
#define SKS   40                // K rows (30 dims + 10 zero pad)
#define KB_STRIDE (NKEY * SKS)  // 5760 u16 per (b,h)
#define VB_STRIDE (32 * SVS)    // 4864 u16 per (b,h)

typedef unsigned short u16;
typedef short v8s __attribute__((ext_vector_type(8)));   // 8 x bf16 MFMA operand
typedef float v4f __attribute__((ext_vector_type(4)));   // 4 x f32 MFMA acc

__device__ __forceinline__ float bf2f(u16 u) {
    union { unsigned int i; float f; } w; w.i = ((unsigned int)u) << 16; return w.f;
}
__device__ __forceinline__ u16 f2bf(float f) {
    union { float f; unsigned int i; } w; w.f = f;
    unsigned int r = w.i + 0x7fffu + ((w.i >> 16) & 1u);
    return (u16)(r >> 16);
}

// ---------------------------------------------------------------------------
// Weight prep: WqT/WpT[j][k] = W[k][j] as bf16, zero-padded to 192x192.
__global__ __launch_bounds__(256) void wt_prep_kernel(
    const float* __restrict__ Wq, const float* __restrict__ Wp,
    u16* __restrict__ WqT, u16* __restrict__ WpT) {
    int idx = blockIdx.x * 256 + threadIdx.x;        // < 2*192*192 = 73728
    int sel = idx >= WPAD * WPAD;
    int rr  = sel ? idx - WPAD * WPAD : idx;
    int j = rr / WPAD, k = rr - j * WPAD;
    const float* W = sel ? Wp : Wq;
    u16* T = sel ? WpT : WqT;
    float v = (j < DIM && k < DIM) ? W[k * DIM + j] : 0.f;
    T[j * WPAD + k] = f2bf(v);
}

// ---------------------------------------------------------------------------
// Bias pre-gather: biasg[h][q][n] = bf16(table[rpi[q,n]][h])
__global__ __launch_bounds__(256) void gather_bias_kernel(
    const float* __restrict__ table, const int* __restrict__ rpi,
    u16* __restrict__ biasg) {
    int idx = blockIdx.x * 256 + threadIdx.x;        // < NGS*NKEY exactly
    int r = rpi[idx];
    int q = idx / NKEY, n = idx - q * NKEY;
#pragma unroll
    for (int h = 0; h < HEADS; ++h)
        biasg[((size_t)h * NGS + q) * NKEY + n] = f2bf(table[r * HEADS + h]);
}

// ---------------------------------------------------------------------------
// K/V projection -> bf16 fragment-ready layouts:
//   Kb [b][h][n][40]  (d padded 30..39 = 0 via memset)
//   VbT[b][h][d][152] (n padded 144..151 = 0, d rows 30,31 = 0 via memset)
__global__ __launch_bounds__(256) void kv_proj_kernel(
    const float* __restrict__ feat,
    const float* __restrict__ Wk, const float* __restrict__ bk,
    const float* __restrict__ Wv, const float* __restrict__ bv,
    u16* __restrict__ Kb, u16* __restrict__ VbT) {
    __shared__ float sF[16 * DIM];
    int b  = blockIdx.x / 9;
    int n0 = (blockIdx.x % 9) * 16;
    int tid = threadIdx.x;
    {
        const float4* src = (const float4*)(feat + (size_t)(b * NKEY + n0) * DIM);
        float4* dst = (float4*)sF;
        for (int i = tid; i < 16 * 45; i += 256) dst[i] = src[i];
    }
    __syncthreads();
    int j = tid;
    if (j < DIM) {
        float ak[16], av[16];
#pragma unroll
        for (int r = 0; r < 16; ++r) { ak[r] = 0.f; av[r] = 0.f; }
        const float4* sF4 = (const float4*)sF;
        for (int kc = 0; kc < 45; ++kc) {
            int kk = kc * 4;
            float wk0 = Wk[(kk + 0) * DIM + j], wk1 = Wk[(kk + 1) * DIM + j];
            float wk2 = Wk[(kk + 2) * DIM + j], wk3 = Wk[(kk + 3) * DIM + j];
            float wv0 = Wv[(kk + 0) * DIM + j], wv1 = Wv[(kk + 1) * DIM + j];
            float wv2 = Wv[(kk + 2) * DIM + j], wv3 = Wv[(kk + 3) * DIM + j];
#pragma unroll
            for (int r = 0; r < 16; ++r) {
                float4 g = sF4[r * 45 + kc];
                ak[r] = fmaf(g.x, wk0, ak[r]); ak[r] = fmaf(g.y, wk1, ak[r]);
                ak[r] = fmaf(g.z, wk2, ak[r]); ak[r] = fmaf(g.w, wk3, ak[r]);
                av[r] = fmaf(g.x, wv0, av[r]); av[r] = fmaf(g.y, wv1, av[r]);
                av[r] = fmaf(g.z, wv2, av[r]); av[r] = fmaf(g.w, wv3, av[r]);
            }
        }
        int h = j / 30, d = j - 30 * h;
        u16* kp = Kb  + (size_t)(b * HEADS + h) * KB_STRIDE;
        u16* vp = VbT + (size_t)(b * HEADS + h) * VB_STRIDE;
        float bkj = bk[j], bvj = bv[j];
#pragma unroll
        for (int r = 0; r < 16; ++r) {
            kp[(n0 + r) * SKS + d] = f2bf(ak[r] + bkj);
            vp[d * SVS + n0 + r]   = f2bf(av[r] + bvj);
        }
    }
}

// ---------------------------------------------------------------------------
// Fused MFMA attention: one block = (batch, 64-query tile).
// LDS: sX 25600 + sQ 25600 + sP 19456 + sV 9728 = 80384 B -> 2 blocks/CU.
//
// NaN-hygiene rule (Round 2 post-mortem): NEVER read uninitialized LDS into an
// MFMA operand, even if the other operand is zero — Inf/NaN garbage * 0 = NaN.
// All pad lanes are either explicitly zeroed or replaced by zero fragments.
__global__ __launch_bounds__(256, 2) void attn_kernel(
    const float* __restrict__ gs,
    const u16* __restrict__ WqT, const float* __restrict__ bq,
    const u16* __restrict__ WpT, const float* __restrict__ bp,
    const u16* __restrict__ Kb, const u16* __restrict__ VbT,
    const u16* __restrict__ biasg, float* __restrict__ out) {

    __shared__ u16 sX[TQ * SXS];   // gs tile (bf16), later attn-output x tile
    __shared__ u16 sQ[TQ * SQS];   // Q rows [q][h*32+d], pads zeroed below
    __shared__ u16 sP[TQ * SPS];   // P rows; first 11520 B alias sK[144][40]
    __shared__ u16 sV[32 * SVS];   // V^T rows [d][n]

    const int tid  = threadIdx.x;
    const int w    = tid >> 6;        // wave 0..3
    const int l15  = tid & 15;
    const int quad = (tid >> 4) & 3;
    const int b    = blockIdx.x / QT;
    const int q0   = (blockIdx.x % QT) * TQ;
    const float SCALE = 0.18257418583505536f;   // 1/sqrt(30)

    // ---- stage gs tile -> sX (bf16, zero pad cols 180..195) ----
    {
        const float4* src = (const float4*)(gs + (size_t)(b * NGS + q0) * DIM);
        for (int i = tid; i < TQ * 45; i += 256) {
            int row = i / 45, c = i - row * 45;
            float4 g = src[row * 45 + c];
            unsigned lo = (unsigned)f2bf(g.x) | ((unsigned)f2bf(g.y) << 16);
            unsigned hi = (unsigned)f2bf(g.z) | ((unsigned)f2bf(g.w) << 16);
            *(uint2*)&sX[row * SXS + c * 4] = make_uint2(lo, hi);
        }
        for (int i = tid; i < TQ * 16; i += 256)
            sX[(i >> 4) * SXS + 180 + (i & 15)] = 0;
    }
    __syncthreads();

    // ---- Q-proj: q = (gs @ Wq + bq)*scale, MFMA, wave w owns j-tiles 3w..3w+2
    {
        v4f acc[12];
#pragma unroll
        for (int i = 0; i < 12; ++i) acc[i] = (v4f){0.f, 0.f, 0.f, 0.f};
        for (int kt = 0; kt < 6; ++kt) {
            v8s A[4];
#pragma unroll
            for (int m = 0; m < 4; ++m)
                A[m] = *(const v8s*)&sX[(16 * m + l15) * SXS + kt * 32 + quad * 8];
#pragma unroll
            for (int jj = 0; jj < 3; ++jj) {
                int j0 = (3 * w + jj) * 16;
                v8s B = *(const v8s*)&WqT[(size_t)(j0 + l15) * WPAD + kt * 32 + quad * 8];
#pragma unroll
                for (int m = 0; m < 4; ++m)
                    acc[jj * 4 + m] = __builtin_amdgcn_mfma_f32_16x16x32_bf16(
                        A[m], B, acc[jj * 4 + m], 0, 0, 0);
            }
        }
#pragma unroll
        for (int jj = 0; jj < 3; ++jj) {
            int j = (3 * w + jj) * 16 + l15;
            if (j < DIM) {
                int h = j / 30;
                int pos = j + 2 * h;          // per-head 32-padded column
                float bqj = bq[j];
#pragma unroll
                for (int m = 0; m < 4; ++m)
#pragma unroll
                    for (int r = 0; r < 4; ++r)
                        sQ[(16 * m + quad * 4 + r) * SQS + pos] =
                            f2bf((acc[jj * 4 + m][r] + bqj) * SCALE);
            }
        }
    }
    // zero Q pad cols d=30,31 of every head slab (qa quad=3 reads them; the
    // matching K dims are zero, but garbage here can be Inf/NaN -> NaN*0=NaN)
    for (int i = tid; i < TQ * HEADS * 2; i += 256) {
        int row = i / 12, c = i - row * 12;
        sQ[row * SQS + (c >> 1) * 32 + 30 + (c & 1)] = 0;
    }
    __syncthreads();

    // ---- per-head attention ----
    for (int h = 0; h < HEADS; ++h) {
        // stage K_h (flat, aliases sP) and V_h^T
        {
            const uint4* ks = (const uint4*)(Kb + (size_t)(b * HEADS + h) * KB_STRIDE);
            uint4* kd = (uint4*)sP;
            for (int i = tid; i < (KB_STRIDE * 2 / 16); i += 256) kd[i] = ks[i];  // 720
            const uint4* vs = (const uint4*)(VbT + (size_t)(b * HEADS + h) * VB_STRIDE);
            uint4* vd = (uint4*)sV;
            for (int i = tid; i < (VB_STRIDE * 2 / 16); i += 256) vd[i] = vs[i];  // 608
        }
        __syncthreads();   // B1: staging (and, for h=0, Q-stores) visible

        // QK^T + bias (as MFMA C operand), wave w owns q rows 16w..16w+15
        v8s qa = *(const v8s*)&sQ[(16 * w + l15) * SQS + h * 32 + quad * 8];
        v4f la[9];
        const u16* bg = biasg + ((size_t)h * NGS + q0 + 16 * w + quad * 4) * NKEY + l15;
#pragma unroll
        for (int t = 0; t < 9; ++t) {
            v4f c;
#pragma unroll
            for (int r = 0; r < 4; ++r) c[r] = bf2f(bg[r * NKEY + t * 16]);
            v8s kb = *(const v8s*)&sP[(16 * t + l15) * SKS + quad * 8];   // sK alias
            la[t] = __builtin_amdgcn_mfma_f32_16x16x32_bf16(qa, kb, c, 0, 0, 0);
        }

        // softmax in registers: row q = 16w + quad*4 + r lives in one 16-lane quad
        float mx[4], sm[4];
#pragma unroll
        for (int r = 0; r < 4; ++r) {
            float m = la[0][r];
#pragma unroll
            for (int t = 1; t < 9; ++t) m = fmaxf(m, la[t][r]);
            m = fmaxf(m, __shfl_xor(m, 1));
            m = fmaxf(m, __shfl_xor(m, 2));
            m = fmaxf(m, __shfl_xor(m, 4));
            m = fmaxf(m, __shfl_xor(m, 8));
            mx[r] = m; sm[r] = 0.f;
        }
#pragma unroll
        for (int t = 0; t < 9; ++t)
#pragma unroll
            for (int r = 0; r < 4; ++r) {
                la[t][r] = __expf(la[t][r] - mx[r]);
                sm[r] += la[t][r];
            }
#pragma unroll
        for (int r = 0; r < 4; ++r) {
            sm[r] += __shfl_xor(sm[r], 1);
            sm[r] += __shfl_xor(sm[r], 2);
            sm[r] += __shfl_xor(sm[r], 4);
            sm[r] += __shfl_xor(sm[r], 8);
            sm[r] = 1.f / sm[r];
        }
        __syncthreads();   // B2: all waves done reading sK region before P overwrite

        // write P (C-layout -> A-layout relayout through LDS)
#pragma unroll
        for (int t = 0; t < 9; ++t)
#pragma unroll
            for (int r = 0; r < 4; ++r)
                sP[(16 * w + quad * 4 + r) * SPS + 16 * t + l15] = f2bf(la[t][r] * sm[r]);
        __syncthreads();   // B3: P visible

        // PV: x_h = P @ V_h. K loop covers 160; the k=144..159 half-tile
        // (kt==4, quad>=2) would read unwritten sP pad (and, for quad==3, the
        // next row) — replace BOTH operands with zero fragments there.
        v4f x0 = (v4f){0.f, 0.f, 0.f, 0.f}, x1 = x0;
        for (int kt = 0; kt < 5; ++kt) {
            v8s pa, vb0, vb1;
            if (kt == 4 && quad >= 2) {
                pa = (v8s){0,0,0,0,0,0,0,0}; vb0 = pa; vb1 = pa;
            } else {
                pa  = *(const v8s*)&sP[(16 * w + l15) * SPS + kt * 32 + quad * 8];
                vb0 = *(const v8s*)&sV[l15 * SVS + kt * 32 + quad * 8];
                vb1 = *(const v8s*)&sV[(16 + l15) * SVS + kt * 32 + quad * 8];
            }
            x0 = __builtin_amdgcn_mfma_f32_16x16x32_bf16(pa, vb0, x0, 0, 0, 0);
            x1 = __builtin_amdgcn_mfma_f32_16x16x32_bf16(pa, vb1, x1, 0, 0, 0);
        }
#pragma unroll
        for (int r = 0; r < 4; ++r) {
            int qrow = (16 * w + quad * 4 + r) * SXS + h * 30;
            sX[qrow + l15] = f2bf(x0[r]);                       // d = l15 < 16
            if (l15 < 14) sX[qrow + 16 + l15] = f2bf(x1[r]);    // d = 16+l15 < 30
        }
        __syncthreads();   // B4: PV reads done (next staging) / x visible
    }

    // ---- out-proj: out = x @ Wp + bp ----
    {
        v4f acc[12];
#pragma unroll
        for (int i = 0; i < 12; ++i) acc[i] = (v4f){0.f, 0.f, 0.f, 0.f};
        for (int kt = 0; kt < 6; ++kt) {
            v8s A[4];
#pragma unroll
            for (int m = 0; m < 4; ++m)
                A[m] = *(const v8s*)&sX[(16 * m + l15) * SXS + kt * 32 + quad * 8];
#pragma unroll
            for (int jj = 0; jj < 3; ++jj) {
                int j0 = (3 * w + jj) * 16;
                v8s B = *(const v8s*)&WpT[(size_t)(j0 + l15) * WPAD + kt * 32 + quad * 8];
#pragma unroll
                for (int m = 0; m < 4; ++m)
                    acc[jj * 4 + m] = __builtin_amdgcn_mfma_f32_16x16x32_bf16(
                        A[m], B, acc[jj * 4 + m], 0, 0, 0);
            }
        }
#pragma unroll
        for (int jj = 0; jj < 3; ++jj) {
            int j = (3 * w + jj) * 16 + l15;
            if (j < DIM) {
                float bpj = bp[j];
#pragma unroll
                for (int m = 0; m < 4; ++m)
#pragma unroll
                    for (int r = 0; r < 4; ++r)
                        out[(size_t)(b * NGS + q0 + 16 * m + quad * 4 + r) * DIM + j] =
                            acc[jj * 4 + m][r] + bpj;
            }
        }
    }
}

// ---------------------------------------------------------------------------
extern "C" void kernel_launch(void* const* d_in, const int* in_sizes, int n_in,
                              void* d_out, int out_size, void* d_ws, size_t ws_size,
                              hipStream_t stream) {
    const float* gs    = (const float*)d_in[0];
    const float* feat  = (const float*)d_in[1];
    const float* Wq    = (const float*)d_in[2];
    const float* bq    = (const float*)d_in[3];
    const float* Wk    = (const float*)d_in[4];
    const float* bk    = (const float*)d_in[5];
    const float* Wv    = (const float*)d_in[6];
    const float* bv    = (const float*)d_in[7];
    const float* Wp    = (const float*)d_in[8];
    const float* bp    = (const float*)d_in[9];
    const float* table = (const float*)d_in[10];
    const int*   rpi   = (const int*)d_in[11];
    float* out = (float*)d_out;

    // ws layout (u16 units): WqT | WpT | Kb | VbT | biasg  (~12.3 MB total)
    u16* WqT   = (u16*)d_ws;
    u16* WpT   = WqT + WPAD * WPAD;
    u16* Kb    = WpT + WPAD * WPAD;
    u16* VbT   = Kb  + (size_t)BATCH * HEADS * KB_STRIDE;
    u16* biasg = VbT + (size_t)BATCH * HEADS * VB_STRIDE;

    // zero K/V pads (d=30.., n=144.. lanes must multiply as 0 in MFMA frags)
    size_t zero_bytes = (size_t)BATCH * HEADS * (KB_STRIDE + VB_STRIDE) * sizeof(u16);
    hipMemsetAsync(Kb, 0, zero_bytes, stream);

    wt_prep_kernel<<<dim3(2 * WPAD * WPAD / 256), dim3(256), 0, stream>>>(Wq, Wp, WqT, WpT);
    gather_bias_kernel<<<dim3(NGS * NKEY / 256), dim3(256), 0, stream>>>(table, rpi, biasg);
    kv_proj_kernel<<<dim3(BATCH * 9), dim3(256), 0, stream>>>(feat, Wk, bk, Wv, bv, Kb, VbT);
    attn_kernel<<<dim3(BATCH * QT), dim3(256), 0, stream>>>(
        gs, WqT, bq, WpT, bp, Kb, VbT, biasg, out);
}

// Round 4
// 381.194 us; speedup vs baseline: 3.2369x; 1.1728x over previous
//
#include <hip/hip_runtime.h>

// Problem constants
#define DIM   180
#define HEADS 6
#define HD    30
#define NKEY  144
#define NGS   2304
#define BATCH 64
#define TQ    64
#define QT    36                // q-tiles (2304/64)
#define WPAD  192               // padded model dim (6 k-tiles of 32)
#define SXS   200               // sXQ row stride u16 (400 B = 25*16, rows 16B-aligned)
#define SPS   152               // sP  row stride u16 (304 B = 19*16)
#define KROW  40                // Kb row stride u16 (80 B, 16B-aligned)
#define VROW  144               // VbT row stride u16 (288 B, 16B-aligned)
#define KB_STRIDE (NKEY * KROW) // 5760 u16 per (b,h)
#define VB_STRIDE (32 * VROW)   // 4608 u16 per (b,h)

typedef unsigned short u16;
typedef short v8s __attribute__((ext_vector_type(8)));   // 8 x bf16 MFMA operand
typedef float v4f __attribute__((ext_vector_type(4)));   // 4 x f32 MFMA acc

__device__ __forceinline__ float bf2f(u16 u) {
    union { unsigned int i; float f; } w; w.i = ((unsigned int)u) << 16; return w.f;
}
__device__ __forceinline__ u16 f2bf(float f) {
    union { float f; unsigned int i; } w; w.f = f;
    unsigned int r = w.i + 0x7fffu + ((w.i >> 16) & 1u);
    return (u16)(r >> 16);
}
__device__ __forceinline__ uint2 pack4(const v4f& x) {
    uint2 r;
    r.x = (unsigned)f2bf(x[0]) | ((unsigned)f2bf(x[1]) << 16);
    r.y = (unsigned)f2bf(x[2]) | ((unsigned)f2bf(x[3]) << 16);
    return r;
}

// ---------------------------------------------------------------------------
// Weight prep: WqT[j][k] = Wq[k][j]; WpT[j][k'] with k' = h*32+dd (32-padded
// head-slab k-layout matching where attn leaves x in LDS), k = h*30+dd.
__global__ __launch_bounds__(256) void wt_prep_kernel(
    const float* __restrict__ Wq, const float* __restrict__ Wp,
    u16* __restrict__ WqT, u16* __restrict__ WpT) {
    int idx = blockIdx.x * 256 + threadIdx.x;        // < 2*192*192
    int sel = idx >= WPAD * WPAD;
    int rr  = sel ? idx - WPAD * WPAD : idx;
    int j = rr / WPAD, k = rr - j * WPAD;
    float v;
    if (!sel) {
        v = (j < DIM && k < DIM) ? Wq[k * DIM + j] : 0.f;
        WqT[j * WPAD + k] = f2bf(v);
    } else {
        int h = k >> 5, dd = k & 31;
        v = (j < DIM && dd < HD) ? Wp[(h * HD + dd) * DIM + j] : 0.f;
        WpT[j * WPAD + k] = f2bf(v);
    }
}

// ---------------------------------------------------------------------------
// Bias pre-gather in S^T C-fragment order: tile (h, g=q/16, t=n/16); lane
// (l15,quad) holds rows n=16t+quad*4+r, col q=16g+l15 (C: col=lane&15,
// row=quad*4+r). One uint2 (4 bf16) per lane -> coalesced dwordx2 in attn.
__global__ __launch_bounds__(256) void gather_bias_kernel(
    const float* __restrict__ table, const int* __restrict__ rpi,
    u16* __restrict__ biasCT) {
    int i = blockIdx.x * 256 + threadIdx.x;          // < 7776*64 = 497664
    int lane = i & 63;
    int tile = i >> 6;
    int t = tile % 9;
    int rem = tile / 9;
    int g = rem % 144;
    int h = rem / 144;
    int q  = 16 * g + (lane & 15);
    int n0 = 16 * t + (lane >> 4) * 4;
    const int4 rr = *(const int4*)&rpi[q * NKEY + n0];
    unsigned lo = (unsigned)f2bf(table[rr.x * HEADS + h]) |
                  ((unsigned)f2bf(table[rr.y * HEADS + h]) << 16);
    unsigned hi = (unsigned)f2bf(table[rr.z * HEADS + h]) |
                  ((unsigned)f2bf(table[rr.w * HEADS + h]) << 16);
    ((uint2*)biasCT)[i] = make_uint2(lo, hi);
}

// ---------------------------------------------------------------------------
// K/V projection -> bf16 fragment-ready global layouts:
//   Kb [b][h][n][40]   (d pad 30..39 = 0 via memset)  -- S^T A-operand rows
//   VbT[b][h][d][144]  (d rows 30,31 = 0 via memset)  -- x^T A-operand rows
__global__ __launch_bounds__(256) void kv_proj_kernel(
    const float* __restrict__ feat,
    const float* __restrict__ Wk, const float* __restrict__ bk,
    const float* __restrict__ Wv, const float* __restrict__ bv,
    u16* __restrict__ Kb, u16* __restrict__ VbT) {
    __shared__ float sF[16 * DIM];
    int b  = blockIdx.x / 9;
    int n0 = (blockIdx.x % 9) * 16;
    int tid = threadIdx.x;
    {
        const float4* src = (const float4*)(feat + (size_t)(b * NKEY + n0) * DIM);
        float4* dst = (float4*)sF;
        for (int i = tid; i < 16 * 45; i += 256) dst[i] = src[i];
    }
    __syncthreads();
    int j = tid;
    if (j < DIM) {
        float ak[16], av[16];
#pragma unroll
        for (int r = 0; r < 16; ++r) { ak[r] = 0.f; av[r] = 0.f; }
        const float4* sF4 = (const float4*)sF;
        for (int kc = 0; kc < 45; ++kc) {
            int kk = kc * 4;
            float wk0 = Wk[(kk + 0) * DIM + j], wk1 = Wk[(kk + 1) * DIM + j];
            float wk2 = Wk[(kk + 2) * DIM + j], wk3 = Wk[(kk + 3) * DIM + j];
            float wv0 = Wv[(kk + 0) * DIM + j], wv1 = Wv[(kk + 1) * DIM + j];
            float wv2 = Wv[(kk + 2) * DIM + j], wv3 = Wv[(kk + 3) * DIM + j];
#pragma unroll
            for (int r = 0; r < 16; ++r) {
                float4 g = sF4[r * 45 + kc];
                ak[r] = fmaf(g.x, wk0, ak[r]); ak[r] = fmaf(g.y, wk1, ak[r]);
                ak[r] = fmaf(g.z, wk2, ak[r]); ak[r] = fmaf(g.w, wk3, ak[r]);
                av[r] = fmaf(g.x, wv0, av[r]); av[r] = fmaf(g.y, wv1, av[r]);
                av[r] = fmaf(g.z, wv2, av[r]); av[r] = fmaf(g.w, wv3, av[r]);
            }
        }
        int h = j / HD, d = j - HD * h;
        u16* kp = Kb  + (size_t)(b * HEADS + h) * KB_STRIDE;
        u16* vp = VbT + (size_t)(b * HEADS + h) * VB_STRIDE;
        float bkj = bk[j], bvj = bv[j];
#pragma unroll
        for (int r = 0; r < 16; ++r) {
            kp[(n0 + r) * KROW + d] = f2bf(ak[r] + bkj);
            vp[d * VROW + n0 + r]   = f2bf(av[r] + bvj);
        }
    }
}

// ---------------------------------------------------------------------------
// Fused MFMA attention. One block = (batch, 64-query tile), 4 waves.
// LDS: sXQ 25600 + sP 19456 = 45056 B -> 3 blocks/CU (12 waves/CU).
// Head loop is BARRIER-FREE: K/V/bias fragments come straight from global
// (L2-resident), P and x touch only wave-private rows. S^T/x^T formulation
// puts each softmax row in one lane (2 shuffles) and makes P/x writes b64.
// NaN-hygiene (R2): every MFMA operand is written data, explicit zeros, or a
// zero register — never uninitialized LDS.
__global__ __launch_bounds__(256, 3) void attn_kernel(
    const float* __restrict__ gs,
    const u16* __restrict__ WqT, const float* __restrict__ bq,
    const u16* __restrict__ WpT, const float* __restrict__ bp,
    const u16* __restrict__ Kb, const u16* __restrict__ VbT,
    const u16* __restrict__ biasCT, float* __restrict__ out) {

    __shared__ u16 sXQ[TQ * SXS];  // gs tile -> Q (head-slab layout) -> x
    __shared__ u16 sP[TQ * SPS];   // P rows [q][n], wave-private 16-row slabs

    const int tid  = threadIdx.x;
    const int w    = tid >> 6;        // wave 0..3
    const int lane = tid & 63;
    const int l15  = tid & 15;
    const int quad = (tid >> 4) & 3;
    const int b    = blockIdx.x / QT;
    const int qt   = blockIdx.x % QT;
    const int q0   = qt * TQ;
    const float SCALE = 0.18257418583505536f;   // 1/sqrt(30)

    // ---- stage gs tile -> sXQ (bf16, zero pad cols 180..195) ----
    {
        const float4* src = (const float4*)(gs + (size_t)(b * NGS + q0) * DIM);
        for (int i = tid; i < TQ * 45; i += 256) {
            int row = i / 45, c = i - row * 45;
            float4 g = src[row * 45 + c];
            unsigned lo = (unsigned)f2bf(g.x) | ((unsigned)f2bf(g.y) << 16);
            unsigned hi = (unsigned)f2bf(g.z) | ((unsigned)f2bf(g.w) << 16);
            *(uint2*)&sXQ[row * SXS + c * 4] = make_uint2(lo, hi);
        }
        for (int i = tid; i < TQ * 16; i += 256)
            sXQ[(i >> 4) * SXS + 180 + (i & 15)] = 0;
    }
    __syncthreads();

    // ---- Q-proj: q = (gs @ Wq + bq)*scale. Accumulate in regs, then
    //      overwrite the (dead) gs tile with Q in 32-padded head-slab cols.
    v4f qacc[12];
#pragma unroll
    for (int i = 0; i < 12; ++i) qacc[i] = (v4f){0.f, 0.f, 0.f, 0.f};
    for (int kt = 0; kt < 6; ++kt) {
        v8s A[4];
#pragma unroll
        for (int m = 0; m < 4; ++m)
            A[m] = *(const v8s*)&sXQ[(16 * m + l15) * SXS + kt * 32 + quad * 8];
#pragma unroll
        for (int jj = 0; jj < 3; ++jj) {
            v8s B = *(const v8s*)&WqT[(size_t)((3 * w + jj) * 16 + l15) * WPAD +
                                      kt * 32 + quad * 8];
#pragma unroll
            for (int m = 0; m < 4; ++m)
                qacc[jj * 4 + m] = __builtin_amdgcn_mfma_f32_16x16x32_bf16(
                    A[m], B, qacc[jj * 4 + m], 0, 0, 0);
        }
    }
    __syncthreads();   // all waves done READING gs before Q overwrites it
#pragma unroll
    for (int jj = 0; jj < 3; ++jj) {
        int j = (3 * w + jj) * 16 + l15;
        if (j < DIM) {
            int h = j / HD;
            int pos = j + 2 * h;          // 32-padded head-slab column
            float bqj = bq[j];
#pragma unroll
            for (int m = 0; m < 4; ++m)
#pragma unroll
                for (int r = 0; r < 4; ++r)
                    sXQ[(16 * m + quad * 4 + r) * SXS + pos] =
                        f2bf((qacc[jj * 4 + m][r] + bqj) * SCALE);
        }
    }
    // zero Q pad cols d=30,31 of every head slab
    for (int i = tid; i < TQ * 12; i += 256) {
        int row = i / 12, c = i - row * 12;
        sXQ[row * SXS + (c >> 1) * 32 + 30 + (c & 1)] = 0;
    }
    __syncthreads();

    // ---- per-head attention (no barriers inside) ----
    for (int h = 0; h < HEADS; ++h) {
        const u16* kp = Kb  + (size_t)(b * HEADS + h) * KB_STRIDE;
        const u16* vp = VbT + (size_t)(b * HEADS + h) * VB_STRIDE;

        // Q B-fragment: own q rows (16w+l15), this head's 32-col slab
        v8s qa = *(const v8s*)&sXQ[(16 * w + l15) * SXS + h * 32 + quad * 8];

        // S^T = K · Q^T + bias^T : A = K rows (lane=n), B = Q (lane=q col).
        // C tile t: row n=16t+quad*4+r, col q=16w+l15.
        v4f la[9];
        const u16* bgt = biasCT +
            ((size_t)((h * 144 + (qt * 4 + w)) * 9) * 256) + lane * 4;
#pragma unroll
        for (int t = 0; t < 9; ++t) {
            uint2 bb = *(const uint2*)(bgt + t * 256);
            v4f c;
            c[0] = bf2f((u16)(bb.x & 0xffff));
            c[1] = bf2f((u16)(bb.x >> 16));
            c[2] = bf2f((u16)(bb.y & 0xffff));
            c[3] = bf2f((u16)(bb.y >> 16));
            v8s kb = *(const v8s*)&kp[(16 * t + l15) * KROW + quad * 8];
            la[t] = __builtin_amdgcn_mfma_f32_16x16x32_bf16(kb, qa, c, 0, 0, 0);
        }

        // softmax: all 36 values in this lane share q = 16w+l15; quads hold
        // disjoint n -> reduce across quads with xor 16,32 only.
        float m = la[0][0];
#pragma unroll
        for (int t = 0; t < 9; ++t)
#pragma unroll
            for (int r = 0; r < 4; ++r) m = fmaxf(m, la[t][r]);
        m = fmaxf(m, __shfl_xor(m, 16));
        m = fmaxf(m, __shfl_xor(m, 32));
        float s = 0.f;
#pragma unroll
        for (int t = 0; t < 9; ++t)
#pragma unroll
            for (int r = 0; r < 4; ++r) {
                la[t][r] = __expf(la[t][r] - m);
                s += la[t][r];
            }
        s += __shfl_xor(s, 16);
        s += __shfl_xor(s, 32);
        float inv = 1.f / s;

        // P -> own 16-row slab of sP, 4 consecutive n per lane = ds_write_b64
#pragma unroll
        for (int t = 0; t < 9; ++t) {
            v4f p;
#pragma unroll
            for (int r = 0; r < 4; ++r) p[r] = la[t][r] * inv;
            *(uint2*)&sP[(16 * w + l15) * SPS + 16 * t + quad * 4] = pack4(p);
        }

        // x^T = V^T · P^T : A = V^T rows (lane=d), B = P rows (lane=q col).
        // k covers n=0..159; the n=144..159 half (kt==4, quad>=2) is skipped
        // via zero regs (sP cols >=144 unwritten; VbT rows end at n=144).
        v4f x0 = (v4f){0.f, 0.f, 0.f, 0.f}, x1 = x0;
        for (int kt = 0; kt < 5; ++kt) {
            v8s pa = (v8s){0,0,0,0,0,0,0,0}, a0 = pa, a1 = pa;
            if (!(kt == 4 && quad >= 2)) {
                pa = *(const v8s*)&sP[(16 * w + l15) * SPS + kt * 32 + quad * 8];
                a0 = *(const v8s*)&vp[l15 * VROW + kt * 32 + quad * 8];
                a1 = *(const v8s*)&vp[(16 + l15) * VROW + kt * 32 + quad * 8];
            }
            x0 = __builtin_amdgcn_mfma_f32_16x16x32_bf16(a0, pa, x0, 0, 0, 0);
            x1 = __builtin_amdgcn_mfma_f32_16x16x32_bf16(a1, pa, x1, 0, 0, 0);
        }
        // x^T C tile: row d=quad*4+r (tile0) / 16+quad*4+r (tile1), col q=l15.
        // Write x[q][h*32+d] into the dead Q slab h; d=30,31 are zero because
        // VbT rows 30,31 are zero. 4 consecutive cols -> ds_write_b64.
        *(uint2*)&sXQ[(16 * w + l15) * SXS + h * 32 + quad * 4]      = pack4(x0);
        *(uint2*)&sXQ[(16 * w + l15) * SXS + h * 32 + 16 + quad * 4] = pack4(x1);
    }
    __syncthreads();   // x rows are read cross-wave by out-proj

    // ---- out-proj: out = x @ Wp + bp (WpT is in matching 32-padded k-layout)
    {
        v4f acc[12];
#pragma unroll
        for (int i = 0; i < 12; ++i) acc[i] = (v4f){0.f, 0.f, 0.f, 0.f};
        for (int kt = 0; kt < 6; ++kt) {
            v8s A[4];
#pragma unroll
            for (int m = 0; m < 4; ++m)
                A[m] = *(const v8s*)&sXQ[(16 * m + l15) * SXS + kt * 32 + quad * 8];
#pragma unroll
            for (int jj = 0; jj < 3; ++jj) {
                v8s B = *(const v8s*)&WpT[(size_t)((3 * w + jj) * 16 + l15) * WPAD +
                                          kt * 32 + quad * 8];
#pragma unroll
                for (int m = 0; m < 4; ++m)
                    acc[jj * 4 + m] = __builtin_amdgcn_mfma_f32_16x16x32_bf16(
                        A[m], B, acc[jj * 4 + m], 0, 0, 0);
            }
        }
#pragma unroll
        for (int jj = 0; jj < 3; ++jj) {
            int j = (3 * w + jj) * 16 + l15;
            if (j < DIM) {
                float bpj = bp[j];
#pragma unroll
                for (int m = 0; m < 4; ++m)
#pragma unroll
                    for (int r = 0; r < 4; ++r)
                        out[(size_t)(b * NGS + q0 + 16 * m + quad * 4 + r) * DIM + j] =
                            acc[jj * 4 + m][r] + bpj;
            }
        }
    }
}

// ---------------------------------------------------------------------------
extern "C" void kernel_launch(void* const* d_in, const int* in_sizes, int n_in,
                              void* d_out, int out_size, void* d_ws, size_t ws_size,
                              hipStream_t stream) {
    const float* gs    = (const float*)d_in[0];
    const float* feat  = (const float*)d_in[1];
    const float* Wq    = (const float*)d_in[2];
    const float* bq    = (const float*)d_in[3];
    const float* Wk    = (const float*)d_in[4];
    const float* bk    = (const float*)d_in[5];
    const float* Wv    = (const float*)d_in[6];
    const float* bv    = (const float*)d_in[7];
    const float* Wp    = (const float*)d_in[8];
    const float* bp    = (const float*)d_in[9];
    const float* table = (const float*)d_in[10];
    const int*   rpi   = (const int*)d_in[11];
    float* out = (float*)d_out;

    // ws layout (u16 units): WqT | WpT | Kb | VbT | biasCT  (~12.1 MB)
    u16* WqT    = (u16*)d_ws;
    u16* WpT    = WqT + WPAD * WPAD;
    u16* Kb     = WpT + WPAD * WPAD;
    u16* VbT    = Kb  + (size_t)BATCH * HEADS * KB_STRIDE;
    u16* biasCT = VbT + (size_t)BATCH * HEADS * VB_STRIDE;

    // zero K pads (d=30..39) and V pad rows (d=30,31): MFMA reads them
    size_t zero_bytes = (size_t)BATCH * HEADS * (KB_STRIDE + VB_STRIDE) * sizeof(u16);
    hipMemsetAsync(Kb, 0, zero_bytes, stream);

    wt_prep_kernel<<<dim3(2 * WPAD * WPAD / 256), dim3(256), 0, stream>>>(Wq, Wp, WqT, WpT);
    gather_bias_kernel<<<dim3(HEADS * 144 * 9 * 64 / 256), dim3(256), 0, stream>>>(
        table, rpi, biasCT);
    kv_proj_kernel<<<dim3(BATCH * 9), dim3(256), 0, stream>>>(feat, Wk, bk, Wv, bv, Kb, VbT);
    attn_kernel<<<dim3(BATCH * QT), dim3(256), 0, stream>>>(
        gs, WqT, bq, WpT, bp, Kb, VbT, biasCT, out);
}